// Round 8
// baseline (326.559 us; speedup 1.0000x reference)
//
#include <hip/hip_runtime.h>
#include <hip/hip_bf16.h>
#include <math.h>

typedef __hip_bfloat16 bf16;
typedef short bf16x8 __attribute__((ext_vector_type(8)));
typedef float f32x4 __attribute__((ext_vector_type(4)));

__device__ __forceinline__ float b2f(bf16 v) { return __bfloat162float(v); }
__device__ __forceinline__ bf16 f2b(float v) { return __float2bfloat16(v); }
__device__ __forceinline__ float us2f(unsigned short u) {
  return __uint_as_float(((unsigned)u) << 16);
}
__device__ __forceinline__ unsigned short f2us(float f) {
  bf16 h = __float2bfloat16(f);
  return *reinterpret_cast<unsigned short*>(&h);
}
__device__ __forceinline__ float ldin(const void* p, size_t i, int f32) {
  return f32 ? ((const float*)p)[i] : b2f(((const bf16*)p)[i]);
}

#define CC 192
#define DD 8
#define HH 32
#define WW 32
#define NHEAD 6
#define HDIM 32
#define HID 768
#define NTOK 8192
#define ATT_SCALE 0.17677669529663687f

// ---------------------------------------------------------------------------
// Weight pre-pass + inline dtype probe. Each block recomputes the flag from
// x's first 256 halfwords (L2-hot, ballot+popcount); block 0 publishes dfl.
// WT[woff + n*K + k] = W[k*N + n] as bf16.  884736 elems.
// ---------------------------------------------------------------------------
__global__ void wconv_kernel(const unsigned short* __restrict__ xu,
                             const void* w0, const void* w1, const void* w2,
                             const void* w3, const void* w4, const void* w5,
                             const void* w6, const void* w7,
                             bf16* __restrict__ WT, int* __restrict__ flag) {
  __shared__ int cnt[4];
  {
    float a = fabsf(us2f(xu[threadIdx.x]));
    bool insane = !((a == 0.0f) || (a > 9.5e-7f && a < 64.0f));
    unsigned long long mask = __ballot(insane);
    if ((threadIdx.x & 63) == 0) cnt[threadIdx.x >> 6] = __popcll(mask);
  }
  __syncthreads();
  int f32 = (cnt[0] + cnt[1] + cnt[2] + cnt[3]) > 32;
  if (blockIdx.x == 0 && threadIdx.x == 0) *flag = f32;

  int idx = blockIdx.x * 256 + threadIdx.x;
  if (idx >= 884736) return;
  const void* src; int K, N, loc;
  if      (idx < 110592) { src = w0; K = 192; N = 576; loc = idx; }
  else if (idx < 147456) { src = w1; K = 192; N = 192; loc = idx - 110592; }
  else if (idx < 294912) { src = w2; K = 192; N = 768; loc = idx - 147456; }
  else if (idx < 442368) { src = w3; K = 768; N = 192; loc = idx - 294912; }
  else if (idx < 552960) { src = w4; K = 192; N = 576; loc = idx - 442368; }
  else if (idx < 589824) { src = w5; K = 192; N = 192; loc = idx - 552960; }
  else if (idx < 737280) { src = w6; K = 192; N = 768; loc = idx - 589824; }
  else                   { src = w7; K = 768; N = 192; loc = idx - 737280; }
  int n = loc / K, k = loc - n * K;
  WT[idx] = f2b(ldin(src, (size_t)k * N + n, f32));
}

#define WOFF_TQKV  0
#define WOFF_TOUT  110592
#define WOFF_TFC1  147456
#define WOFF_TFC2  294912
#define WOFF_SQKV  442368
#define WOFF_SPROJ 552960
#define WOFF_SFC1  589824
#define WOFF_SFC2  737280

// ---------------------------------------------------------------------------
// Fused: T[r,c] = x[c,d,h,w] + pos[d,c];  Y = LN(T)   (wave per row)
// ---------------------------------------------------------------------------
__global__ void build_ln1_kernel(const void* __restrict__ x, const void* __restrict__ pos,
                                 const void* __restrict__ g, const void* __restrict__ b,
                                 float* __restrict__ T, bf16* __restrict__ Y,
                                 const int* __restrict__ dfl) {
  int f32 = *dfl;
  int wave = (blockIdx.x * blockDim.x + threadIdx.x) >> 6;
  int lane = threadIdx.x & 63;
  if (wave >= NTOK) return;
  int d = wave & 7, hw = wave >> 3;
  float v[3];
#pragma unroll
  for (int e = 0; e < 3; e++) {
    int c = lane + e * 64;
    v[e] = ldin(x, (size_t)((c << 3) + d) * 1024 + hw, f32) +
           ldin(pos, (size_t)d * CC + c, f32);
  }
  float* tr = T + (size_t)wave * CC;
#pragma unroll
  for (int e = 0; e < 3; e++) tr[lane + e * 64] = v[e];
  float s = v[0] + v[1] + v[2];
  for (int off = 32; off; off >>= 1) s += __shfl_xor(s, off);
  float mean = s * (1.0f / CC);
  float d0 = v[0] - mean, d1 = v[1] - mean, d2 = v[2] - mean;
  float q = d0 * d0 + d1 * d1 + d2 * d2;
  for (int off = 32; off; off >>= 1) q += __shfl_xor(q, off);
  float rstd = rsqrtf(q * (1.0f / CC) + 1e-5f);
  bf16* o = Y + (size_t)wave * CC;
  o[lane]       = f2b(d0 * rstd * ldin(g, lane, f32)       + ldin(b, lane, f32));
  o[lane + 64]  = f2b(d1 * rstd * ldin(g, lane + 64, f32)  + ldin(b, lane + 64, f32));
  o[lane + 128] = f2b(d2 * rstd * ldin(g, lane + 128, f32) + ldin(b, lane + 128, f32));
}

// ---------------------------------------------------------------------------
// MFMA GEMM (BN=64): A bf16 [M,K], WT bf16 [N,K]. BK=64. TM in {1,2}.
// FINAL: dst[col*NTOK+row] = v + X2[row*CC+col] (dtype by flag)
// ---------------------------------------------------------------------------
template <int TM, bool BIAS, bool GELU, bool RES, bool OUTBF, bool FINAL>
__global__ void gemm_kernel(const bf16* __restrict__ A, const bf16* __restrict__ WT,
                            const void* __restrict__ bias, const float* __restrict__ R,
                            void* __restrict__ Cout, const float* __restrict__ X2,
                            int M, int N, int K, const int* __restrict__ dfl) {
  int f32 = *dfl;
  __shared__ __align__(16) unsigned short As[TM * 64 * 72];
  __shared__ __align__(16) unsigned short Bs[64 * 72];
  int bm = blockIdx.y * (TM * 64), bn = blockIdx.x * 64;
  int tid = threadIdx.x;
  int w = tid >> 6;
  int lane = tid & 63;
  int lm = lane & 15;
  int lk = lane >> 4;

  f32x4 acc[TM][4];
#pragma unroll
  for (int i = 0; i < TM; i++)
#pragma unroll
    for (int j = 0; j < 4; j++) acc[i][j] = (f32x4){0.f, 0.f, 0.f, 0.f};

  const unsigned short* Au = reinterpret_cast<const unsigned short*>(A);
  const unsigned short* Wu = reinterpret_cast<const unsigned short*>(WT);

  for (int k0 = 0; k0 < K; k0 += 64) {
#pragma unroll
    for (int u = 0; u < TM * 2; u++) {
      int unit = tid + u * 256;
      int row = unit >> 3, seg = unit & 7;
      uint4 v = *reinterpret_cast<const uint4*>(
          &Au[(size_t)(bm + row) * K + k0 + seg * 8]);
      *reinterpret_cast<uint4*>(&As[row * 72 + seg * 8]) = v;
    }
#pragma unroll
    for (int u = 0; u < 2; u++) {
      int unit = tid + u * 256;
      int n = unit >> 3, seg = unit & 7;
      uint4 v = *reinterpret_cast<const uint4*>(
          &Wu[(size_t)(bn + n) * K + k0 + seg * 8]);
      *reinterpret_cast<uint4*>(&Bs[n * 72 + seg * 8]) = v;
    }
    __syncthreads();

#pragma unroll
    for (int kc = 0; kc < 2; kc++) {
      bf16x8 af[TM], bfr[4];
#pragma unroll
      for (int tm = 0; tm < TM; tm++)
        af[tm] = *reinterpret_cast<const bf16x8*>(
            &As[(w * (TM * 16) + tm * 16 + lm) * 72 + kc * 32 + lk * 8]);
#pragma unroll
      for (int tn = 0; tn < 4; tn++)
        bfr[tn] = *reinterpret_cast<const bf16x8*>(
            &Bs[(tn * 16 + lm) * 72 + kc * 32 + lk * 8]);
#pragma unroll
      for (int tm = 0; tm < TM; tm++)
#pragma unroll
        for (int tn = 0; tn < 4; tn++)
          acc[tm][tn] = __builtin_amdgcn_mfma_f32_16x16x32_bf16(
              af[tm], bfr[tn], acc[tm][tn], 0, 0, 0);
    }
    __syncthreads();
  }

#pragma unroll
  for (int tn = 0; tn < 4; tn++) {
    int col = bn + tn * 16 + lm;
    float bv = BIAS ? ldin(bias, col, f32) : 0.f;
#pragma unroll
    for (int tm = 0; tm < TM; tm++) {
      int row0 = bm + w * (TM * 16) + tm * 16 + lk * 4;
#pragma unroll
      for (int r = 0; r < 4; r++) {
        int row = row0 + r;
        float v = acc[tm][tn][r];
        if (BIAS) v += bv;
        if (GELU) v = 0.5f * v * (1.0f + erff(v * 0.70710678118654752f));
        size_t idx = (size_t)row * N + col;
        if (RES) v += R[idx];
        if (FINAL) {
          float o = v + X2[(size_t)row * CC + col];
          if (f32) ((float*)Cout)[(size_t)col * NTOK + row] = o;
          else     ((bf16*)Cout)[(size_t)col * NTOK + row] = f2b(o);
        } else if (OUTBF) {
          ((bf16*)Cout)[idx] = f2b(v);
        } else {
          ((float*)Cout)[idx] = v;
        }
      }
    }
  }
}

// ---------------------------------------------------------------------------
// MFMA GEMM with fused row-LN epilogue. N=192 (full row per block),
// 64 rows/block, 4 waves x 16 rows x 12 col-frags. BK=64.
// Epilogue: v = acc + bias + R[row]  ->  Fout fp32, then LN(v) -> Yout bf16.
// EPI variant (time fc2): v = t-row; lnf(v)*gf+bf + x  -> X1T (space order),
// then s_ln1 of that -> Yout (space order).
// Row LN: per-lane partial over 12 frags, shfl_xor {1,2,4,8} over 16 lanes.
// ---------------------------------------------------------------------------
template <bool EPI>
__global__ void gemm_ln_kernel(const bf16* __restrict__ A, const bf16* __restrict__ WT,
                               const void* __restrict__ bias, const float* __restrict__ R,
                               const void* __restrict__ x,
                               const void* __restrict__ g0, const void* __restrict__ b0,
                               const void* __restrict__ g1, const void* __restrict__ b1,
                               float* __restrict__ Fout, bf16* __restrict__ Yout,
                               int K, const int* __restrict__ dfl) {
  int f32 = *dfl;
  __shared__ __align__(16) unsigned short As[64 * 72];
  __shared__ __align__(16) unsigned short Bs[192 * 72];
  int bm = blockIdx.x * 64;
  int tid = threadIdx.x;
  int w = tid >> 6;
  int lane = tid & 63;
  int lm = lane & 15;
  int lk = lane >> 4;

  f32x4 acc[12];
#pragma unroll
  for (int j = 0; j < 12; j++) acc[j] = (f32x4){0.f, 0.f, 0.f, 0.f};

  const unsigned short* Au = reinterpret_cast<const unsigned short*>(A);
  const unsigned short* Wu = reinterpret_cast<const unsigned short*>(WT);

  for (int k0 = 0; k0 < K; k0 += 64) {
#pragma unroll
    for (int u = 0; u < 2; u++) {
      int unit = tid + u * 256;
      int row = unit >> 3, seg = unit & 7;
      uint4 v = *reinterpret_cast<const uint4*>(
          &Au[(size_t)(bm + row) * K + k0 + seg * 8]);
      *reinterpret_cast<uint4*>(&As[row * 72 + seg * 8]) = v;
    }
#pragma unroll
    for (int u = 0; u < 6; u++) {
      int unit = tid + u * 256;
      int n = unit >> 3, seg = unit & 7;
      uint4 v = *reinterpret_cast<const uint4*>(
          &Wu[(size_t)n * K + k0 + seg * 8]);
      *reinterpret_cast<uint4*>(&Bs[n * 72 + seg * 8]) = v;
    }
    __syncthreads();

#pragma unroll
    for (int kc = 0; kc < 2; kc++) {
      bf16x8 af = *reinterpret_cast<const bf16x8*>(
          &As[(w * 16 + lm) * 72 + kc * 32 + lk * 8]);
#pragma unroll
      for (int tn = 0; tn < 12; tn++) {
        bf16x8 bfr = *reinterpret_cast<const bf16x8*>(
            &Bs[(tn * 16 + lm) * 72 + kc * 32 + lk * 8]);
        acc[tn] = __builtin_amdgcn_mfma_f32_16x16x32_bf16(af, bfr, acc[tn], 0, 0, 0);
      }
    }
    __syncthreads();
  }

  // bias per col frag
  float bv[12];
#pragma unroll
  for (int tn = 0; tn < 12; tn++) bv[tn] = ldin(bias, tn * 16 + lm, f32);

#pragma unroll
  for (int r = 0; r < 4; r++) {
    int row = bm + w * 16 + lk * 4 + r;
    float v[12];
    float s = 0.f;
#pragma unroll
    for (int tn = 0; tn < 12; tn++) {
      float t = acc[tn][r] + bv[tn] + R[(size_t)row * CC + tn * 16 + lm];
      v[tn] = t;
      s += t;
    }
    for (int off = 1; off < 16; off <<= 1) s += __shfl_xor(s, off);
    float mean = s * (1.0f / CC);
    float q = 0.f;
#pragma unroll
    for (int tn = 0; tn < 12; tn++) { float d = v[tn] - mean; q += d * d; }
    for (int off = 1; off < 16; off <<= 1) q += __shfl_xor(q, off);
    float rstd = rsqrtf(q * (1.0f / CC) + 1e-5f);

    if (!EPI) {
#pragma unroll
      for (int tn = 0; tn < 12; tn++) {
        int col = tn * 16 + lm;
        Fout[(size_t)row * CC + col] = v[tn];
        Yout[(size_t)row * CC + col] =
            f2b((v[tn] - mean) * rstd * ldin(g0, col, f32) + ldin(b0, col, f32));
      }
    } else {
      int d = row & 7, hw = row >> 3;
      int m = d * 1024 + hw;
      float xv[12];
      float s2 = 0.f;
#pragma unroll
      for (int tn = 0; tn < 12; tn++) {
        int col = tn * 16 + lm;
        float normed = (v[tn] - mean) * rstd * ldin(g0, col, f32) + ldin(b0, col, f32);
        float t = ldin(x, (size_t)((col << 3) + d) * 1024 + hw, f32) + normed;
        xv[tn] = t;
        s2 += t;
        Fout[(size_t)m * CC + col] = t;
      }
      for (int off = 1; off < 16; off <<= 1) s2 += __shfl_xor(s2, off);
      float mean2 = s2 * (1.0f / CC);
      float q2 = 0.f;
#pragma unroll
      for (int tn = 0; tn < 12; tn++) { float dd = xv[tn] - mean2; q2 += dd * dd; }
      for (int off = 1; off < 16; off <<= 1) q2 += __shfl_xor(q2, off);
      float rstd2 = rsqrtf(q2 * (1.0f / CC) + 1e-5f);
#pragma unroll
      for (int tn = 0; tn < 12; tn++) {
        int col = tn * 16 + lm;
        Yout[(size_t)m * CC + col] =
            f2b((xv[tn] - mean2) * rstd2 * ldin(g1, col, f32) + ldin(b1, col, f32));
      }
    }
  }
}

// ---------------------------------------------------------------------------
// Time attention: one block per sequence n (1024), 192 threads
// ---------------------------------------------------------------------------
__global__ void time_attn_kernel(const bf16* __restrict__ qkv, bf16* __restrict__ O) {
  __shared__ float q[NHEAD][DD][HDIM];
  __shared__ float k[NHEAD][DD][HDIM];
  __shared__ float v[NHEAD][DD][HDIM];
  __shared__ float p[NHEAD][DD][DD];
  int n = blockIdx.x;
  int head = threadIdx.x >> 5;
  int dd = threadIdx.x & 31;
  for (int s = 0; s < DD; s++) {
    const bf16* row = qkv + (size_t)(n * DD + s) * (3 * CC);
    q[head][s][dd] = b2f(row[head * HDIM + dd]);
    k[head][s][dd] = b2f(row[CC + head * HDIM + dd]);
    v[head][s][dd] = b2f(row[2 * CC + head * HDIM + dd]);
  }
  __syncthreads();
  for (int pair = dd; pair < 64; pair += 32) {
    int sq = pair >> 3, sk = pair & 7;
    float sum = 0.f;
#pragma unroll
    for (int e = 0; e < HDIM; e++) sum += q[head][sq][e] * k[head][sk][e];
    p[head][sq][sk] = sum * ATT_SCALE;
  }
  __syncthreads();
  if (dd < DD) {
    float mx = -1e30f;
    for (int sk = 0; sk < DD; sk++) mx = fmaxf(mx, p[head][dd][sk]);
    float sum = 0.f;
    for (int sk = 0; sk < DD; sk++) { float e = expf(p[head][dd][sk] - mx); p[head][dd][sk] = e; sum += e; }
    float inv = 1.0f / sum;
    for (int sk = 0; sk < DD; sk++) p[head][dd][sk] *= inv;
  }
  __syncthreads();
  for (int sq = 0; sq < DD; sq++) {
    float sum = 0.f;
#pragma unroll
    for (int sk = 0; sk < DD; sk++) sum += p[head][sq][sk] * v[head][sk][dd];
    O[(size_t)(n * DD + sq) * CC + head * HDIM + dd] = f2b(sum);
  }
}

// ---------------------------------------------------------------------------
// MFMA NAT attention (proven r6). Block = (frame, 8x8 tile, head), 768 blocks.
// ---------------------------------------------------------------------------
#define NKEY 224
#define PKS 40
#define PVS 232
__global__ void nat_attn_kernel(const bf16* __restrict__ qkv, const void* __restrict__ rpb,
                                bf16* __restrict__ O, const int* __restrict__ dfl) {
  int f32 = *dfl;
  __shared__ __align__(16) unsigned short Ks[NKEY * PKS];
  __shared__ __align__(16) unsigned short Vs[32 * PVS];
  __shared__ __align__(16) unsigned short Qs[64 * PKS];
  __shared__ __align__(16) unsigned short Ps[64 * PVS];
  __shared__ float rb[176];

  int blk = blockIdx.x;
  int frame = blk & 7;
  int rest = blk >> 3;
  int h = rest % 6;
  int tile = rest / 6;
  int ty = tile >> 2, tx = tile & 3;
  int base_h = min(max(ty * 8 - 3, 0), HH - 7);
  int base_w = min(max(tx * 8 - 3, 0), WW - 7);

  int tid = threadIdx.x;

  for (int i = tid; i < 169; i += 256) rb[i] = ldin(rpb, (size_t)h * 169 + i, f32);
  for (int u = tid; u < 784; u += 256) {
    int j = u >> 2, seg = u & 3;
    int a = j / 14, bb = j - a * 14;
    int ih = min(base_h + a, HH - 1), iw = min(base_w + bb, WW - 1);
    int mg = frame * 1024 + ih * 32 + iw;
    uint4 v = *reinterpret_cast<const uint4*>(qkv + (size_t)mg * 576 + 192 + h * 32 + seg * 8);
    *reinterpret_cast<uint4*>(&Ks[j * PKS + seg * 8]) = v;
  }
  for (int u = tid; u < 784; u += 256) {
    int j = u >> 2, seg = u & 3;
    int a = j / 14, bb = j - a * 14;
    int ih = min(base_h + a, HH - 1), iw = min(base_w + bb, WW - 1);
    int mg = frame * 1024 + ih * 32 + iw;
    uint4 v = *reinterpret_cast<const uint4*>(qkv + (size_t)mg * 576 + 384 + h * 32 + seg * 8);
    unsigned arr[4] = {v.x, v.y, v.z, v.w};
#pragma unroll
    for (int e = 0; e < 4; e++) {
      Vs[(seg * 8 + e * 2) * PVS + j]     = (unsigned short)(arr[e] & 0xffffu);
      Vs[(seg * 8 + e * 2 + 1) * PVS + j] = (unsigned short)(arr[e] >> 16);
    }
  }
  for (int u = tid; u < 32 * (PVS - 196); u += 256) {
    int dd = u / (PVS - 196), c = 196 + u % (PVS - 196);
    Vs[dd * PVS + c] = 0;
  }
  {
    int q = tid >> 2, seg = tid & 3;
    int qy = ty * 8 + (q >> 3), qx = tx * 8 + (q & 7);
    int mg = frame * 1024 + qy * 32 + qx;
    uint4 v = *reinterpret_cast<const uint4*>(qkv + (size_t)mg * 576 + h * 32 + seg * 8);
    *reinterpret_cast<uint4*>(&Qs[q * PKS + seg * 8]) = v;
  }
  __syncthreads();

  int w = tid >> 6;
  int lane = tid & 63;
  int c = lane & 15;
  int lk = lane >> 4;

  bf16x8 aq = *reinterpret_cast<const bf16x8*>(&Qs[(w * 16 + c) * PKS + lk * 8]);
  f32x4 sc[14];
#pragma unroll
  for (int f = 0; f < 14; f++) {
    bf16x8 bk = *reinterpret_cast<const bf16x8*>(&Ks[(f * 16 + c) * PKS + lk * 8]);
    sc[f] = __builtin_amdgcn_mfma_f32_16x16x32_bf16(aq, bk, (f32x4){0.f, 0.f, 0.f, 0.f}, 0, 0, 0);
  }

#pragma unroll
  for (int f = 0; f < 14; f++) {
    int key = f * 16 + c;
    int a = key / 14, bb = key - a * 14;
    int ih = base_h + a, iw = base_w + bb;
    bool keyok = key < 196;
#pragma unroll
    for (int r = 0; r < 4; r++) {
      int qloc = w * 16 + lk * 4 + r;
      int qy = ty * 8 + (qloc >> 3), qx = tx * 8 + (qloc & 7);
      int sh = min(max(qy - 3, 0), HH - 7);
      int sw = min(max(qx - 3, 0), WW - 7);
      bool valid = keyok && ((unsigned)(ih - sh) < 7u) && ((unsigned)(iw - sw) < 7u);
      int bidx = valid ? (ih - qy + 6) * 13 + (iw - qx + 6) : 0;
      float s = sc[f][r] * ATT_SCALE + rb[bidx];
      sc[f][r] = valid ? s : -1e30f;
    }
  }

  float sm[4];
#pragma unroll
  for (int r = 0; r < 4; r++) {
    float m = sc[0][r];
#pragma unroll
    for (int f = 1; f < 14; f++) m = fmaxf(m, sc[f][r]);
    for (int off = 8; off; off >>= 1) m = fmaxf(m, __shfl_xor(m, off));
    float s = 0.f;
#pragma unroll
    for (int f = 0; f < 14; f++) { float e = __expf(sc[f][r] - m); sc[f][r] = e; s += e; }
    for (int off = 8; off; off >>= 1) s += __shfl_xor(s, off);
    sm[r] = 1.0f / s;
  }
#pragma unroll
  for (int f = 0; f < 14; f++)
#pragma unroll
    for (int r = 0; r < 4; r++)
      Ps[(w * 16 + lk * 4 + r) * PVS + f * 16 + c] = f2us(sc[f][r] * sm[r]);
  __syncthreads();

  f32x4 oacc[2] = {(f32x4){0.f, 0.f, 0.f, 0.f}, (f32x4){0.f, 0.f, 0.f, 0.f}};
#pragma unroll
  for (int kt = 0; kt < 7; kt++) {
    bf16x8 ap = *reinterpret_cast<const bf16x8*>(&Ps[(w * 16 + c) * PVS + kt * 32 + lk * 8]);
#pragma unroll
    for (int dt = 0; dt < 2; dt++) {
      bf16x8 bv = *reinterpret_cast<const bf16x8*>(&Vs[(dt * 16 + c) * PVS + kt * 32 + lk * 8]);
      oacc[dt] = __builtin_amdgcn_mfma_f32_16x16x32_bf16(ap, bv, oacc[dt], 0, 0, 0);
    }
  }

#pragma unroll
  for (int dt = 0; dt < 2; dt++)
#pragma unroll
    for (int r = 0; r < 4; r++) {
      int qloc = w * 16 + lk * 4 + r;
      int qy = ty * 8 + (qloc >> 3), qx = tx * 8 + (qloc & 7);
      int mg = frame * 1024 + qy * 32 + qx;
      O[(size_t)mg * CC + h * 32 + dt * 16 + c] = f2b(oacc[dt][r]);
    }
}

// ---------------------------------------------------------------------------
extern "C" void kernel_launch(void* const* d_in, const int* in_sizes, int n_in,
                              void* d_out, int out_size, void* d_ws, size_t ws_size,
                              hipStream_t stream) {
  const void* x        = d_in[0];
  const void* pos_emb  = d_in[1];
  const void* t_ln1_g  = d_in[2];
  const void* t_ln1_b  = d_in[3];
  const void* t_qkv_w  = d_in[4];
  const void* t_out_w  = d_in[5];
  const void* t_out_b  = d_in[6];
  const void* t_ln2_g  = d_in[7];
  const void* t_ln2_b  = d_in[8];
  const void* t_fc1_w  = d_in[9];
  const void* t_fc1_b  = d_in[10];
  const void* t_fc2_w  = d_in[11];
  const void* t_fc2_b  = d_in[12];
  const void* t_lnf_g  = d_in[13];
  const void* t_lnf_b  = d_in[14];
  const void* s_ln1_g  = d_in[15];
  const void* s_ln1_b  = d_in[16];
  const void* s_qkv_w  = d_in[17];
  const void* s_qkv_b  = d_in[18];
  const void* s_rpb    = d_in[19];
  const void* s_proj_w = d_in[20];
  const void* s_proj_b = d_in[21];
  const void* s_ln2_g  = d_in[22];
  const void* s_ln2_b  = d_in[23];
  const void* s_fc1_w  = d_in[24];
  const void* s_fc1_b  = d_in[25];
  const void* s_fc2_w  = d_in[26];
  const void* s_fc2_b  = d_in[27];

  // Workspace: [0,SZ) f32 T/S | [SZ,2SZ) f32 X1T | [2SZ,2.5SZ) bf16 Y |
  // [2.5SZ,3SZ) bf16 O | [3SZ,5SZ) bf16 QKV/Hb | [5SZ] dfl | WT bf16.
  float* ws = (float*)d_ws;
  const size_t SZ = (size_t)NTOK * CC;
  const size_t need = (5 * SZ + 4 + 442368 + 16) * sizeof(float);
  if (ws_size < need) return;

  float* T   = ws;
  float* X1T = ws + SZ;
  bf16*  Y   = (bf16*)(ws + 2 * SZ);
  bf16*  O   = (bf16*)(ws + 2 * SZ + SZ / 2);
  bf16*  QKV = (bf16*)(ws + 3 * SZ);
  bf16*  Hb  = QKV;
  float* S   = T;
  int*   dfl = (int*)(ws + 5 * SZ);
  bf16*  WT  = (bf16*)(ws + 5 * SZ + 4);

  dim3 blk256(256);

  wconv_kernel<<<3456, blk256, 0, stream>>>(
      (const unsigned short*)x,
      t_qkv_w, t_out_w, t_fc1_w, t_fc2_w, s_qkv_w, s_proj_w, s_fc1_w, s_fc2_w, WT, dfl);

  // ---- Time transformer ----
  build_ln1_kernel<<<NTOK / 4, blk256, 0, stream>>>(x, pos_emb, t_ln1_g, t_ln1_b, T, Y, dfl);
  gemm_kernel<2, false, false, false, true, false><<<dim3(9, 64), blk256, 0, stream>>>(
      Y, WT + WOFF_TQKV, nullptr, nullptr, QKV, nullptr, NTOK, 3 * CC, CC, dfl);
  time_attn_kernel<<<1024, 192, 0, stream>>>(QKV, O);
  // out-proj + residual + ln2 fused
  gemm_ln_kernel<false><<<128, blk256, 0, stream>>>(
      O, WT + WOFF_TOUT, t_out_b, T, nullptr, t_ln2_g, t_ln2_b, nullptr, nullptr,
      T, Y, CC, dfl);
  gemm_kernel<2, true, true, false, true, false><<<dim3(12, 64), blk256, 0, stream>>>(
      Y, WT + WOFF_TFC1, t_fc1_b, nullptr, Hb, nullptr, NTOK, HID, CC, dfl);
  // fc2 + residual + lnf + x-add + s_ln1 fused
  gemm_ln_kernel<true><<<128, blk256, 0, stream>>>(
      Hb, WT + WOFF_TFC2, t_fc2_b, T, x, t_lnf_g, t_lnf_b, s_ln1_g, s_ln1_b,
      X1T, Y, HID, dfl);

  // ---- Space transformer ----
  gemm_kernel<2, true, false, false, true, false><<<dim3(9, 64), blk256, 0, stream>>>(
      Y, WT + WOFF_SQKV, s_qkv_b, nullptr, QKV, nullptr, NTOK, 3 * CC, CC, dfl);
  nat_attn_kernel<<<768, blk256, 0, stream>>>(QKV, s_rpb, O, dfl);
  // proj + residual + ln2 fused
  gemm_ln_kernel<false><<<128, blk256, 0, stream>>>(
      O, WT + WOFF_SPROJ, s_proj_b, X1T, nullptr, s_ln2_g, s_ln2_b, nullptr, nullptr,
      S, Y, CC, dfl);
  gemm_kernel<2, true, true, false, true, false><<<dim3(12, 64), blk256, 0, stream>>>(
      Y, WT + WOFF_SFC1, s_fc1_b, nullptr, Hb, nullptr, NTOK, HID, CC, dfl);
  gemm_kernel<1, true, false, true, false, true><<<dim3(3, 128), blk256, 0, stream>>>(
      Hb, WT + WOFF_SFC2, s_fc2_b, S, d_out, X1T, NTOK, CC, HID, dfl);
}

// Round 9
// 311.893 us; speedup vs baseline: 1.0470x; 1.0470x over previous
//
#include <hip/hip_runtime.h>
#include <hip/hip_bf16.h>
#include <math.h>

typedef __hip_bfloat16 bf16;
typedef short bf16x8 __attribute__((ext_vector_type(8)));
typedef float f32x4 __attribute__((ext_vector_type(4)));

__device__ __forceinline__ float b2f(bf16 v) { return __bfloat162float(v); }
__device__ __forceinline__ bf16 f2b(float v) { return __float2bfloat16(v); }
__device__ __forceinline__ float us2f(unsigned short u) {
  return __uint_as_float(((unsigned)u) << 16);
}
__device__ __forceinline__ unsigned short f2us(float f) {
  bf16 h = __float2bfloat16(f);
  return *reinterpret_cast<unsigned short*>(&h);
}
__device__ __forceinline__ float ldin(const void* p, size_t i, int f32) {
  return f32 ? ((const float*)p)[i] : b2f(((const bf16*)p)[i]);
}

#define CC 192
#define DD 8
#define HH 32
#define WW 32
#define NHEAD 6
#define HDIM 32
#define HID 768
#define NTOK 8192
#define ATT_SCALE 0.17677669529663687f

// ---------------------------------------------------------------------------
// Weight pre-pass + inline dtype probe (proven r8).
// WT[woff + n*K + k] = W[k*N + n] as bf16.  884736 elems.
// ---------------------------------------------------------------------------
__global__ void wconv_kernel(const unsigned short* __restrict__ xu,
                             const void* w0, const void* w1, const void* w2,
                             const void* w3, const void* w4, const void* w5,
                             const void* w6, const void* w7,
                             bf16* __restrict__ WT, int* __restrict__ flag) {
  __shared__ int cnt[4];
  {
    float a = fabsf(us2f(xu[threadIdx.x]));
    bool insane = !((a == 0.0f) || (a > 9.5e-7f && a < 64.0f));
    unsigned long long mask = __ballot(insane);
    if ((threadIdx.x & 63) == 0) cnt[threadIdx.x >> 6] = __popcll(mask);
  }
  __syncthreads();
  int f32 = (cnt[0] + cnt[1] + cnt[2] + cnt[3]) > 32;
  if (blockIdx.x == 0 && threadIdx.x == 0) *flag = f32;

  int idx = blockIdx.x * 256 + threadIdx.x;
  if (idx >= 884736) return;
  const void* src; int K, N, loc;
  if      (idx < 110592) { src = w0; K = 192; N = 576; loc = idx; }
  else if (idx < 147456) { src = w1; K = 192; N = 192; loc = idx - 110592; }
  else if (idx < 294912) { src = w2; K = 192; N = 768; loc = idx - 147456; }
  else if (idx < 442368) { src = w3; K = 768; N = 192; loc = idx - 294912; }
  else if (idx < 552960) { src = w4; K = 192; N = 576; loc = idx - 442368; }
  else if (idx < 589824) { src = w5; K = 192; N = 192; loc = idx - 552960; }
  else if (idx < 737280) { src = w6; K = 192; N = 768; loc = idx - 589824; }
  else                   { src = w7; K = 768; N = 192; loc = idx - 737280; }
  int n = loc / K, k = loc - n * K;
  WT[idx] = f2b(ldin(src, (size_t)k * N + n, f32));
}

#define WOFF_TQKV  0
#define WOFF_TOUT  110592
#define WOFF_TFC1  147456
#define WOFF_TFC2  294912
#define WOFF_SQKV  442368
#define WOFF_SPROJ 552960
#define WOFF_SFC1  589824
#define WOFF_SFC2  737280

// ---------------------------------------------------------------------------
// Fused: T[r,c] = x[c,d,h,w] + pos[d,c];  Y = LN(T)   (wave per row; proven)
// ---------------------------------------------------------------------------
__global__ void build_ln1_kernel(const void* __restrict__ x, const void* __restrict__ pos,
                                 const void* __restrict__ g, const void* __restrict__ b,
                                 float* __restrict__ T, bf16* __restrict__ Y,
                                 const int* __restrict__ dfl) {
  int f32 = *dfl;
  int wave = (blockIdx.x * blockDim.x + threadIdx.x) >> 6;
  int lane = threadIdx.x & 63;
  if (wave >= NTOK) return;
  int d = wave & 7, hw = wave >> 3;
  float v[3];
#pragma unroll
  for (int e = 0; e < 3; e++) {
    int c = lane + e * 64;
    v[e] = ldin(x, (size_t)((c << 3) + d) * 1024 + hw, f32) +
           ldin(pos, (size_t)d * CC + c, f32);
  }
  float* tr = T + (size_t)wave * CC;
#pragma unroll
  for (int e = 0; e < 3; e++) tr[lane + e * 64] = v[e];
  float s = v[0] + v[1] + v[2];
  for (int off = 32; off; off >>= 1) s += __shfl_xor(s, off);
  float mean = s * (1.0f / CC);
  float d0 = v[0] - mean, d1 = v[1] - mean, d2 = v[2] - mean;
  float q = d0 * d0 + d1 * d1 + d2 * d2;
  for (int off = 32; off; off >>= 1) q += __shfl_xor(q, off);
  float rstd = rsqrtf(q * (1.0f / CC) + 1e-5f);
  bf16* o = Y + (size_t)wave * CC;
  o[lane]       = f2b(d0 * rstd * ldin(g, lane, f32)       + ldin(b, lane, f32));
  o[lane + 64]  = f2b(d1 * rstd * ldin(g, lane + 64, f32)  + ldin(b, lane + 64, f32));
  o[lane + 128] = f2b(d2 * rstd * ldin(g, lane + 128, f32) + ldin(b, lane + 128, f32));
}

// ---------------------------------------------------------------------------
// MFMA GEMM (proven r7): A bf16 [M,K], WT bf16 [N,K]. BK=64. TM in {1,2}.
// FINAL: dst[col*NTOK+row] = v + X2[row*CC+col] (dtype by flag)
// ---------------------------------------------------------------------------
template <int TM, bool BIAS, bool GELU, bool RES, bool OUTBF, bool FINAL>
__global__ void gemm_kernel(const bf16* __restrict__ A, const bf16* __restrict__ WT,
                            const void* __restrict__ bias, const float* __restrict__ R,
                            void* __restrict__ Cout, const float* __restrict__ X2,
                            int M, int N, int K, const int* __restrict__ dfl) {
  int f32 = *dfl;
  __shared__ __align__(16) unsigned short As[TM * 64 * 72];
  __shared__ __align__(16) unsigned short Bs[64 * 72];
  int bm = blockIdx.y * (TM * 64), bn = blockIdx.x * 64;
  int tid = threadIdx.x;
  int w = tid >> 6;
  int lane = tid & 63;
  int lm = lane & 15;
  int lk = lane >> 4;

  f32x4 acc[TM][4];
#pragma unroll
  for (int i = 0; i < TM; i++)
#pragma unroll
    for (int j = 0; j < 4; j++) acc[i][j] = (f32x4){0.f, 0.f, 0.f, 0.f};

  const unsigned short* Au = reinterpret_cast<const unsigned short*>(A);
  const unsigned short* Wu = reinterpret_cast<const unsigned short*>(WT);

  for (int k0 = 0; k0 < K; k0 += 64) {
#pragma unroll
    for (int u = 0; u < TM * 2; u++) {
      int unit = tid + u * 256;
      int row = unit >> 3, seg = unit & 7;
      uint4 v = *reinterpret_cast<const uint4*>(
          &Au[(size_t)(bm + row) * K + k0 + seg * 8]);
      *reinterpret_cast<uint4*>(&As[row * 72 + seg * 8]) = v;
    }
#pragma unroll
    for (int u = 0; u < 2; u++) {
      int unit = tid + u * 256;
      int n = unit >> 3, seg = unit & 7;
      uint4 v = *reinterpret_cast<const uint4*>(
          &Wu[(size_t)(bn + n) * K + k0 + seg * 8]);
      *reinterpret_cast<uint4*>(&Bs[n * 72 + seg * 8]) = v;
    }
    __syncthreads();

#pragma unroll
    for (int kc = 0; kc < 2; kc++) {
      bf16x8 af[TM], bfr[4];
#pragma unroll
      for (int tm = 0; tm < TM; tm++)
        af[tm] = *reinterpret_cast<const bf16x8*>(
            &As[(w * (TM * 16) + tm * 16 + lm) * 72 + kc * 32 + lk * 8]);
#pragma unroll
      for (int tn = 0; tn < 4; tn++)
        bfr[tn] = *reinterpret_cast<const bf16x8*>(
            &Bs[(tn * 16 + lm) * 72 + kc * 32 + lk * 8]);
#pragma unroll
      for (int tm = 0; tm < TM; tm++)
#pragma unroll
        for (int tn = 0; tn < 4; tn++)
          acc[tm][tn] = __builtin_amdgcn_mfma_f32_16x16x32_bf16(
              af[tm], bfr[tn], acc[tm][tn], 0, 0, 0);
    }
    __syncthreads();
  }

#pragma unroll
  for (int tn = 0; tn < 4; tn++) {
    int col = bn + tn * 16 + lm;
    float bv = BIAS ? ldin(bias, col, f32) : 0.f;
#pragma unroll
    for (int tm = 0; tm < TM; tm++) {
      int row0 = bm + w * (TM * 16) + tm * 16 + lk * 4;
#pragma unroll
      for (int r = 0; r < 4; r++) {
        int row = row0 + r;
        float v = acc[tm][tn][r];
        if (BIAS) v += bv;
        if (GELU) v = 0.5f * v * (1.0f + erff(v * 0.70710678118654752f));
        size_t idx = (size_t)row * N + col;
        if (RES) v += R[idx];
        if (FINAL) {
          float o = v + X2[(size_t)row * CC + col];
          if (f32) ((float*)Cout)[(size_t)col * NTOK + row] = o;
          else     ((bf16*)Cout)[(size_t)col * NTOK + row] = f2b(o);
        } else if (OUTBF) {
          ((bf16*)Cout)[idx] = f2b(v);
        } else {
          ((float*)Cout)[idx] = v;
        }
      }
    }
  }
}

// ---------------------------------------------------------------------------
// fc1 GEMM with LN fused into A-staging. A = fp32 residual [M,192].
// Per block: 128 rows x 64 cols of HID. K=192 staged once (LN'd, bf16),
// then 6 kc-chunks of MFMA. Grid (12,64) = 768 blocks. GELU+bias epilogue.
// LN: 4 thr/row, 48 fp32 each, 2-shfl stats, normalize w/ gb in LDS.
// ---------------------------------------------------------------------------
#define FSTR 200   // As/Bs row stride (elems)
__global__ void gemm_fc1ln_kernel(const float* __restrict__ A, const bf16* __restrict__ WT,
                                  const void* __restrict__ g, const void* __restrict__ b,
                                  const void* __restrict__ bias,
                                  bf16* __restrict__ Hb, const int* __restrict__ dfl) {
  int f32 = *dfl;
  __shared__ __align__(16) unsigned short As[128 * FSTR];
  __shared__ __align__(16) unsigned short Bs[64 * FSTR];
  __shared__ float gb[384];
  int bm = blockIdx.y * 128, bn = blockIdx.x * 64;
  int tid = threadIdx.x;

  // stage LN params
  for (int i = tid; i < 384; i += 256)
    gb[i] = (i < 192) ? ldin(g, i, f32) : ldin(b, i - 192, f32);
  // stage W^T: 64 rows x 192 k = 1536 16B-units, 6/thread
  const unsigned short* Wu = reinterpret_cast<const unsigned short*>(WT);
#pragma unroll
  for (int u = 0; u < 6; u++) {
    int unit = tid + u * 256;
    int n = unit / 24, seg = unit - n * 24;
    uint4 v = *reinterpret_cast<const uint4*>(&Wu[(size_t)(bn + n) * 192 + seg * 8]);
    *reinterpret_cast<uint4*>(&Bs[n * FSTR + seg * 8]) = v;
  }
  __syncthreads();  // gb ready before normalize below

  // stage A with LN: 2 passes x 64 rows, 4 threads/row (48 fp32 each)
#pragma unroll
  for (int p = 0; p < 2; p++) {
    int rowloc = p * 64 + (tid >> 2);
    int q = tid & 3;
    const float* ar = A + (size_t)(bm + rowloc) * 192 + q * 48;
    float v[48];
    float s = 0.f;
#pragma unroll
    for (int i = 0; i < 12; i++) {
      float4 f4 = *reinterpret_cast<const float4*>(ar + i * 4);
      v[i * 4] = f4.x; v[i * 4 + 1] = f4.y; v[i * 4 + 2] = f4.z; v[i * 4 + 3] = f4.w;
      s += f4.x + f4.y + f4.z + f4.w;
    }
    s += __shfl_xor(s, 1); s += __shfl_xor(s, 2);
    float mean = s * (1.0f / 192.0f);
    float qv = 0.f;
#pragma unroll
    for (int i = 0; i < 48; i++) { float d = v[i] - mean; qv += d * d; }
    qv += __shfl_xor(qv, 1); qv += __shfl_xor(qv, 2);
    float rstd = rsqrtf(qv * (1.0f / 192.0f) + 1e-5f);
#pragma unroll
    for (int i = 0; i < 6; i++) {
      uint4 pk;
      unsigned* pu = reinterpret_cast<unsigned*>(&pk);
#pragma unroll
      for (int e = 0; e < 4; e++) {
        int i0 = i * 8 + e * 2;
        int c0 = q * 48 + i0;
        unsigned lo = f2us((v[i0]     - mean) * rstd * gb[c0]     + gb[192 + c0]);
        unsigned hi = f2us((v[i0 + 1] - mean) * rstd * gb[c0 + 1] + gb[192 + c0 + 1]);
        pu[e] = lo | (hi << 16);
      }
      *reinterpret_cast<uint4*>(&As[rowloc * FSTR + q * 48 + i * 8]) = pk;
    }
  }
  __syncthreads();

  int w = tid >> 6;
  int lane = tid & 63;
  int lm = lane & 15;
  int lk = lane >> 4;

  f32x4 acc[2][4];
#pragma unroll
  for (int i = 0; i < 2; i++)
#pragma unroll
    for (int j = 0; j < 4; j++) acc[i][j] = (f32x4){0.f, 0.f, 0.f, 0.f};

#pragma unroll
  for (int kc = 0; kc < 6; kc++) {
    bf16x8 af[2], bfr[4];
#pragma unroll
    for (int tm = 0; tm < 2; tm++)
      af[tm] = *reinterpret_cast<const bf16x8*>(
          &As[(w * 32 + tm * 16 + lm) * FSTR + kc * 32 + lk * 8]);
#pragma unroll
    for (int tn = 0; tn < 4; tn++)
      bfr[tn] = *reinterpret_cast<const bf16x8*>(
          &Bs[(tn * 16 + lm) * FSTR + kc * 32 + lk * 8]);
#pragma unroll
    for (int tm = 0; tm < 2; tm++)
#pragma unroll
      for (int tn = 0; tn < 4; tn++)
        acc[tm][tn] = __builtin_amdgcn_mfma_f32_16x16x32_bf16(
            af[tm], bfr[tn], acc[tm][tn], 0, 0, 0);
  }

#pragma unroll
  for (int tn = 0; tn < 4; tn++) {
    int col = bn + tn * 16 + lm;
    float bv = ldin(bias, col, f32);
#pragma unroll
    for (int tm = 0; tm < 2; tm++) {
      int row0 = bm + w * 32 + tm * 16 + lk * 4;
#pragma unroll
      for (int r = 0; r < 4; r++) {
        float v = acc[tm][tn][r] + bv;
        v = 0.5f * v * (1.0f + erff(v * 0.70710678118654752f));
        Hb[(size_t)(row0 + r) * HID + col] = f2b(v);
      }
    }
  }
}

// ---------------------------------------------------------------------------
// Time attention (proven): one block per sequence n (1024), 192 threads
// ---------------------------------------------------------------------------
__global__ void time_attn_kernel(const bf16* __restrict__ qkv, bf16* __restrict__ O) {
  __shared__ float q[NHEAD][DD][HDIM];
  __shared__ float k[NHEAD][DD][HDIM];
  __shared__ float v[NHEAD][DD][HDIM];
  __shared__ float p[NHEAD][DD][DD];
  int n = blockIdx.x;
  int head = threadIdx.x >> 5;
  int dd = threadIdx.x & 31;
  for (int s = 0; s < DD; s++) {
    const bf16* row = qkv + (size_t)(n * DD + s) * (3 * CC);
    q[head][s][dd] = b2f(row[head * HDIM + dd]);
    k[head][s][dd] = b2f(row[CC + head * HDIM + dd]);
    v[head][s][dd] = b2f(row[2 * CC + head * HDIM + dd]);
  }
  __syncthreads();
  for (int pair = dd; pair < 64; pair += 32) {
    int sq = pair >> 3, sk = pair & 7;
    float sum = 0.f;
#pragma unroll
    for (int e = 0; e < HDIM; e++) sum += q[head][sq][e] * k[head][sk][e];
    p[head][sq][sk] = sum * ATT_SCALE;
  }
  __syncthreads();
  if (dd < DD) {
    float mx = -1e30f;
    for (int sk = 0; sk < DD; sk++) mx = fmaxf(mx, p[head][dd][sk]);
    float sum = 0.f;
    for (int sk = 0; sk < DD; sk++) { float e = expf(p[head][dd][sk] - mx); p[head][dd][sk] = e; sum += e; }
    float inv = 1.0f / sum;
    for (int sk = 0; sk < DD; sk++) p[head][dd][sk] *= inv;
  }
  __syncthreads();
  for (int sq = 0; sq < DD; sq++) {
    float sum = 0.f;
#pragma unroll
    for (int sk = 0; sk < DD; sk++) sum += p[head][sq][sk] * v[head][sk][dd];
    O[(size_t)(n * DD + sq) * CC + head * HDIM + dd] = f2b(sum);
  }
}

// ---------------------------------------------------------------------------
// Fused time epilogue + space ln1 (proven r7)
// ---------------------------------------------------------------------------
__global__ void epi_ln1_kernel(const float* __restrict__ T, const void* __restrict__ x,
                               const void* __restrict__ gf, const void* __restrict__ bf,
                               const void* __restrict__ g1, const void* __restrict__ b1,
                               float* __restrict__ X1T, bf16* __restrict__ Y,
                               const int* __restrict__ dfl) {
  int f32 = *dfl;
  int wave = (blockIdx.x * blockDim.x + threadIdx.x) >> 6;
  int lane = threadIdx.x & 63;
  if (wave >= NTOK) return;
  const float* r = T + (size_t)wave * CC;
  float v0 = r[lane], v1 = r[lane + 64], v2 = r[lane + 128];
  float s = v0 + v1 + v2;
  for (int off = 32; off; off >>= 1) s += __shfl_xor(s, off);
  float mean = s * (1.0f / CC);
  float d0 = v0 - mean, d1 = v1 - mean, d2 = v2 - mean;
  float q = d0 * d0 + d1 * d1 + d2 * d2;
  for (int off = 32; off; off >>= 1) q += __shfl_xor(q, off);
  float rstd = rsqrtf(q * (1.0f / CC) + 1e-5f);
  int d = wave & 7, hw = wave >> 3;
  int m = d * 1024 + hw;
  float xv[3];
#pragma unroll
  for (int e = 0; e < 3; e++) {
    int c = lane + e * 64;
    float dv = (e == 0 ? d0 : (e == 1 ? d1 : d2));
    float normed = dv * rstd * ldin(gf, c, f32) + ldin(bf, c, f32);
    xv[e] = ldin(x, (size_t)((c << 3) + d) * 1024 + hw, f32) + normed;
  }
  float* o = X1T + (size_t)m * CC;
#pragma unroll
  for (int e = 0; e < 3; e++) o[lane + e * 64] = xv[e];
  float s2 = xv[0] + xv[1] + xv[2];
  for (int off = 32; off; off >>= 1) s2 += __shfl_xor(s2, off);
  float mean2 = s2 * (1.0f / CC);
  float e0 = xv[0] - mean2, e1 = xv[1] - mean2, e2 = xv[2] - mean2;
  float q2 = e0 * e0 + e1 * e1 + e2 * e2;
  for (int off = 32; off; off >>= 1) q2 += __shfl_xor(q2, off);
  float rstd2 = rsqrtf(q2 * (1.0f / CC) + 1e-5f);
  bf16* y = Y + (size_t)m * CC;
  y[lane]       = f2b(e0 * rstd2 * ldin(g1, lane, f32)       + ldin(b1, lane, f32));
  y[lane + 64]  = f2b(e1 * rstd2 * ldin(g1, lane + 64, f32)  + ldin(b1, lane + 64, f32));
  y[lane + 128] = f2b(e2 * rstd2 * ldin(g1, lane + 128, f32) + ldin(b1, lane + 128, f32));
}

// ---------------------------------------------------------------------------
// MFMA NAT attention (proven r6). Block = (frame, 8x8 tile, head), 768 blocks.
// ---------------------------------------------------------------------------
#define NKEY 224
#define PKS 40
#define PVS 232
__global__ void nat_attn_kernel(const bf16* __restrict__ qkv, const void* __restrict__ rpb,
                                bf16* __restrict__ O, const int* __restrict__ dfl) {
  int f32 = *dfl;
  __shared__ __align__(16) unsigned short Ks[NKEY * PKS];
  __shared__ __align__(16) unsigned short Vs[32 * PVS];
  __shared__ __align__(16) unsigned short Qs[64 * PKS];
  __shared__ __align__(16) unsigned short Ps[64 * PVS];
  __shared__ float rb[176];

  int blk = blockIdx.x;
  int frame = blk & 7;
  int rest = blk >> 3;
  int h = rest % 6;
  int tile = rest / 6;
  int ty = tile >> 2, tx = tile & 3;
  int base_h = min(max(ty * 8 - 3, 0), HH - 7);
  int base_w = min(max(tx * 8 - 3, 0), WW - 7);

  int tid = threadIdx.x;

  for (int i = tid; i < 169; i += 256) rb[i] = ldin(rpb, (size_t)h * 169 + i, f32);
  for (int u = tid; u < 784; u += 256) {
    int j = u >> 2, seg = u & 3;
    int a = j / 14, bb = j - a * 14;
    int ih = min(base_h + a, HH - 1), iw = min(base_w + bb, WW - 1);
    int mg = frame * 1024 + ih * 32 + iw;
    uint4 v = *reinterpret_cast<const uint4*>(qkv + (size_t)mg * 576 + 192 + h * 32 + seg * 8);
    *reinterpret_cast<uint4*>(&Ks[j * PKS + seg * 8]) = v;
  }
  for (int u = tid; u < 784; u += 256) {
    int j = u >> 2, seg = u & 3;
    int a = j / 14, bb = j - a * 14;
    int ih = min(base_h + a, HH - 1), iw = min(base_w + bb, WW - 1);
    int mg = frame * 1024 + ih * 32 + iw;
    uint4 v = *reinterpret_cast<const uint4*>(qkv + (size_t)mg * 576 + 384 + h * 32 + seg * 8);
    unsigned arr[4] = {v.x, v.y, v.z, v.w};
#pragma unroll
    for (int e = 0; e < 4; e++) {
      Vs[(seg * 8 + e * 2) * PVS + j]     = (unsigned short)(arr[e] & 0xffffu);
      Vs[(seg * 8 + e * 2 + 1) * PVS + j] = (unsigned short)(arr[e] >> 16);
    }
  }
  for (int u = tid; u < 32 * (PVS - 196); u += 256) {
    int dd = u / (PVS - 196), c = 196 + u % (PVS - 196);
    Vs[dd * PVS + c] = 0;
  }
  {
    int q = tid >> 2, seg = tid & 3;
    int qy = ty * 8 + (q >> 3), qx = tx * 8 + (q & 7);
    int mg = frame * 1024 + qy * 32 + qx;
    uint4 v = *reinterpret_cast<const uint4*>(qkv + (size_t)mg * 576 + h * 32 + seg * 8);
    *reinterpret_cast<uint4*>(&Qs[q * PKS + seg * 8]) = v;
  }
  __syncthreads();

  int w = tid >> 6;
  int lane = tid & 63;
  int c = lane & 15;
  int lk = lane >> 4;

  bf16x8 aq = *reinterpret_cast<const bf16x8*>(&Qs[(w * 16 + c) * PKS + lk * 8]);
  f32x4 sc[14];
#pragma unroll
  for (int f = 0; f < 14; f++) {
    bf16x8 bk = *reinterpret_cast<const bf16x8*>(&Ks[(f * 16 + c) * PKS + lk * 8]);
    sc[f] = __builtin_amdgcn_mfma_f32_16x16x32_bf16(aq, bk, (f32x4){0.f, 0.f, 0.f, 0.f}, 0, 0, 0);
  }

#pragma unroll
  for (int f = 0; f < 14; f++) {
    int key = f * 16 + c;
    int a = key / 14, bb = key - a * 14;
    int ih = base_h + a, iw = base_w + bb;
    bool keyok = key < 196;
#pragma unroll
    for (int r = 0; r < 4; r++) {
      int qloc = w * 16 + lk * 4 + r;
      int qy = ty * 8 + (qloc >> 3), qx = tx * 8 + (qloc & 7);
      int sh = min(max(qy - 3, 0), HH - 7);
      int sw = min(max(qx - 3, 0), WW - 7);
      bool valid = keyok && ((unsigned)(ih - sh) < 7u) && ((unsigned)(iw - sw) < 7u);
      int bidx = valid ? (ih - qy + 6) * 13 + (iw - qx + 6) : 0;
      float s = sc[f][r] * ATT_SCALE + rb[bidx];
      sc[f][r] = valid ? s : -1e30f;
    }
  }

  float sm[4];
#pragma unroll
  for (int r = 0; r < 4; r++) {
    float m = sc[0][r];
#pragma unroll
    for (int f = 1; f < 14; f++) m = fmaxf(m, sc[f][r]);
    for (int off = 8; off; off >>= 1) m = fmaxf(m, __shfl_xor(m, off));
    float s = 0.f;
#pragma unroll
    for (int f = 0; f < 14; f++) { float e = __expf(sc[f][r] - m); sc[f][r] = e; s += e; }
    for (int off = 8; off; off >>= 1) s += __shfl_xor(s, off);
    sm[r] = 1.0f / s;
  }
#pragma unroll
  for (int f = 0; f < 14; f++)
#pragma unroll
    for (int r = 0; r < 4; r++)
      Ps[(w * 16 + lk * 4 + r) * PVS + f * 16 + c] = f2us(sc[f][r] * sm[r]);
  __syncthreads();

  f32x4 oacc[2] = {(f32x4){0.f, 0.f, 0.f, 0.f}, (f32x4){0.f, 0.f, 0.f, 0.f}};
#pragma unroll
  for (int kt = 0; kt < 7; kt++) {
    bf16x8 ap = *reinterpret_cast<const bf16x8*>(&Ps[(w * 16 + c) * PVS + kt * 32 + lk * 8]);
#pragma unroll
    for (int dt = 0; dt < 2; dt++) {
      bf16x8 bv = *reinterpret_cast<const bf16x8*>(&Vs[(dt * 16 + c) * PVS + kt * 32 + lk * 8]);
      oacc[dt] = __builtin_amdgcn_mfma_f32_16x16x32_bf16(ap, bv, oacc[dt], 0, 0, 0);
    }
  }

#pragma unroll
  for (int dt = 0; dt < 2; dt++)
#pragma unroll
    for (int r = 0; r < 4; r++) {
      int qloc = w * 16 + lk * 4 + r;
      int qy = ty * 8 + (qloc >> 3), qx = tx * 8 + (qloc & 7);
      int mg = frame * 1024 + qy * 32 + qx;
      O[(size_t)mg * CC + h * 32 + dt * 16 + c] = f2b(oacc[dt][r]);
    }
}

// ---------------------------------------------------------------------------
extern "C" void kernel_launch(void* const* d_in, const int* in_sizes, int n_in,
                              void* d_out, int out_size, void* d_ws, size_t ws_size,
                              hipStream_t stream) {
  const void* x        = d_in[0];
  const void* pos_emb  = d_in[1];
  const void* t_ln1_g  = d_in[2];
  const void* t_ln1_b  = d_in[3];
  const void* t_qkv_w  = d_in[4];
  const void* t_out_w  = d_in[5];
  const void* t_out_b  = d_in[6];
  const void* t_ln2_g  = d_in[7];
  const void* t_ln2_b  = d_in[8];
  const void* t_fc1_w  = d_in[9];
  const void* t_fc1_b  = d_in[10];
  const void* t_fc2_w  = d_in[11];
  const void* t_fc2_b  = d_in[12];
  const void* t_lnf_g  = d_in[13];
  const void* t_lnf_b  = d_in[14];
  const void* s_ln1_g  = d_in[15];
  const void* s_ln1_b  = d_in[16];
  const void* s_qkv_w  = d_in[17];
  const void* s_qkv_b  = d_in[18];
  const void* s_rpb    = d_in[19];
  const void* s_proj_w = d_in[20];
  const void* s_proj_b = d_in[21];
  const void* s_ln2_g  = d_in[22];
  const void* s_ln2_b  = d_in[23];
  const void* s_fc1_w  = d_in[24];
  const void* s_fc1_b  = d_in[25];
  const void* s_fc2_w  = d_in[26];
  const void* s_fc2_b  = d_in[27];

  float* ws = (float*)d_ws;
  const size_t SZ = (size_t)NTOK * CC;
  const size_t need = (5 * SZ + 4 + 442368 + 16) * sizeof(float);
  if (ws_size < need) return;

  float* T   = ws;
  float* X1T = ws + SZ;
  bf16*  Y   = (bf16*)(ws + 2 * SZ);
  bf16*  O   = (bf16*)(ws + 2 * SZ + SZ / 2);
  bf16*  QKV = (bf16*)(ws + 3 * SZ);
  bf16*  Hb  = QKV;
  float* S   = T;
  int*   dfl = (int*)(ws + 5 * SZ);
  bf16*  WT  = (bf16*)(ws + 5 * SZ + 4);

  dim3 blk256(256);

  wconv_kernel<<<3456, blk256, 0, stream>>>(
      (const unsigned short*)x,
      t_qkv_w, t_out_w, t_fc1_w, t_fc2_w, s_qkv_w, s_proj_w, s_fc1_w, s_fc2_w, WT, dfl);

  // ---- Time transformer ----
  build_ln1_kernel<<<NTOK / 4, blk256, 0, stream>>>(x, pos_emb, t_ln1_g, t_ln1_b, T, Y, dfl);
  gemm_kernel<2, false, false, false, true, false><<<dim3(9, 64), blk256, 0, stream>>>(
      Y, WT + WOFF_TQKV, nullptr, nullptr, QKV, nullptr, NTOK, 3 * CC, CC, dfl);
  time_attn_kernel<<<1024, 192, 0, stream>>>(QKV, O);
  gemm_kernel<1, true, false, true, false, false><<<dim3(3, 128), blk256, 0, stream>>>(
      O, WT + WOFF_TOUT, t_out_b, T, T, nullptr, NTOK, CC, CC, dfl);
  gemm_fc1ln_kernel<<<dim3(12, 64), blk256, 0, stream>>>(
      T, WT + WOFF_TFC1, t_ln2_g, t_ln2_b, t_fc1_b, Hb, dfl);
  gemm_kernel<1, true, false, true, false, false><<<dim3(3, 128), blk256, 0, stream>>>(
      Hb, WT + WOFF_TFC2, t_fc2_b, T, T, nullptr, NTOK, CC, HID, dfl);
  epi_ln1_kernel<<<NTOK / 4, blk256, 0, stream>>>(
      T, x, t_lnf_g, t_lnf_b, s_ln1_g, s_ln1_b, X1T, Y, dfl);

  // ---- Space transformer ----
  gemm_kernel<2, true, false, false, true, false><<<dim3(9, 64), blk256, 0, stream>>>(
      Y, WT + WOFF_SQKV, s_qkv_b, nullptr, QKV, nullptr, NTOK, 3 * CC, CC, dfl);
  nat_attn_kernel<<<768, blk256, 0, stream>>>(QKV, s_rpb, O, dfl);
  gemm_kernel<1, true, false, true, false, false><<<dim3(3, 128), blk256, 0, stream>>>(
      O, WT + WOFF_SPROJ, s_proj_b, X1T, S, nullptr, NTOK, CC, CC, dfl);
  gemm_fc1ln_kernel<<<dim3(12, 64), blk256, 0, stream>>>(
      S, WT + WOFF_SFC1, s_ln2_g, s_ln2_b, s_fc1_b, Hb, dfl);
  gemm_kernel<1, true, false, true, false, true><<<dim3(3, 128), blk256, 0, stream>>>(
      Hb, WT + WOFF_SFC2, s_fc2_b, S, d_out, X1T, NTOK, CC, HID, dfl);
}

// Round 10
// 274.163 us; speedup vs baseline: 1.1911x; 1.1376x over previous
//
#include <hip/hip_runtime.h>
#include <hip/hip_bf16.h>
#include <math.h>

typedef __hip_bfloat16 bf16;
typedef short bf16x8 __attribute__((ext_vector_type(8)));
typedef float f32x4 __attribute__((ext_vector_type(4)));

__device__ __forceinline__ float b2f(bf16 v) { return __bfloat162float(v); }
__device__ __forceinline__ bf16 f2b(float v) { return __float2bfloat16(v); }
__device__ __forceinline__ float us2f(unsigned short u) {
  return __uint_as_float(((unsigned)u) << 16);
}
__device__ __forceinline__ unsigned short f2us(float f) {
  bf16 h = __float2bfloat16(f);
  return *reinterpret_cast<unsigned short*>(&h);
}
__device__ __forceinline__ float ldin(const void* p, size_t i, int f32) {
  return f32 ? ((const float*)p)[i] : b2f(((const bf16*)p)[i]);
}

#define CC 192
#define DD 8
#define HH 32
#define WW 32
#define NHEAD 6
#define HDIM 32
#define HID 768
#define NTOK 8192
#define ATT_SCALE 0.17677669529663687f

// ---------------------------------------------------------------------------
// Weight pre-pass + inline dtype probe. Each block recomputes the flag from
// x's first 256 halfwords (L2-hot); block 0 publishes dfl for later kernels.
// WT[woff + n*K + k] = W[k*N + n] as bf16.  884736 elems.
// ---------------------------------------------------------------------------
__global__ void wconv_kernel(const unsigned short* __restrict__ xu,
                             const void* w0, const void* w1, const void* w2,
                             const void* w3, const void* w4, const void* w5,
                             const void* w6, const void* w7,
                             bf16* __restrict__ WT, int* __restrict__ flag) {
  __shared__ int cnt[4];
  {
    float a = fabsf(us2f(xu[threadIdx.x]));
    bool insane = !((a == 0.0f) || (a > 9.5e-7f && a < 64.0f));
    unsigned long long mask = __ballot(insane);
    if ((threadIdx.x & 63) == 0) cnt[threadIdx.x >> 6] = __popcll(mask);
  }
  __syncthreads();
  int f32 = (cnt[0] + cnt[1] + cnt[2] + cnt[3]) > 32;
  if (blockIdx.x == 0 && threadIdx.x == 0) *flag = f32;

  int idx = blockIdx.x * 256 + threadIdx.x;
  if (idx >= 884736) return;
  const void* src; int K, N, loc;
  if      (idx < 110592) { src = w0; K = 192; N = 576; loc = idx; }
  else if (idx < 147456) { src = w1; K = 192; N = 192; loc = idx - 110592; }
  else if (idx < 294912) { src = w2; K = 192; N = 768; loc = idx - 147456; }
  else if (idx < 442368) { src = w3; K = 768; N = 192; loc = idx - 294912; }
  else if (idx < 552960) { src = w4; K = 192; N = 576; loc = idx - 442368; }
  else if (idx < 589824) { src = w5; K = 192; N = 192; loc = idx - 552960; }
  else if (idx < 737280) { src = w6; K = 192; N = 768; loc = idx - 589824; }
  else                   { src = w7; K = 768; N = 192; loc = idx - 737280; }
  int n = loc / K, k = loc - n * K;
  WT[idx] = f2b(ldin(src, (size_t)k * N + n, f32));
}

#define WOFF_TQKV  0
#define WOFF_TOUT  110592
#define WOFF_TFC1  147456
#define WOFF_TFC2  294912
#define WOFF_SQKV  442368
#define WOFF_SPROJ 552960
#define WOFF_SFC1  589824
#define WOFF_SFC2  737280

// ---------------------------------------------------------------------------
// Fused: T[r,c] = x[c,d,h,w] + pos[d,c];  Y = LN(T)   (wave per row; proven)
// ---------------------------------------------------------------------------
__global__ void build_ln1_kernel(const void* __restrict__ x, const void* __restrict__ pos,
                                 const void* __restrict__ g, const void* __restrict__ b,
                                 float* __restrict__ T, bf16* __restrict__ Y,
                                 const int* __restrict__ dfl) {
  int f32 = *dfl;
  int wave = (blockIdx.x * blockDim.x + threadIdx.x) >> 6;
  int lane = threadIdx.x & 63;
  if (wave >= NTOK) return;
  int d = wave & 7, hw = wave >> 3;
  float v[3];
#pragma unroll
  for (int e = 0; e < 3; e++) {
    int c = lane + e * 64;
    v[e] = ldin(x, (size_t)((c << 3) + d) * 1024 + hw, f32) +
           ldin(pos, (size_t)d * CC + c, f32);
  }
  float* tr = T + (size_t)wave * CC;
#pragma unroll
  for (int e = 0; e < 3; e++) tr[lane + e * 64] = v[e];
  float s = v[0] + v[1] + v[2];
  for (int off = 32; off; off >>= 1) s += __shfl_xor(s, off);
  float mean = s * (1.0f / CC);
  float d0 = v[0] - mean, d1 = v[1] - mean, d2 = v[2] - mean;
  float q = d0 * d0 + d1 * d1 + d2 * d2;
  for (int off = 32; off; off >>= 1) q += __shfl_xor(q, off);
  float rstd = rsqrtf(q * (1.0f / CC) + 1e-5f);
  bf16* o = Y + (size_t)wave * CC;
  o[lane]       = f2b(d0 * rstd * ldin(g, lane, f32)       + ldin(b, lane, f32));
  o[lane + 64]  = f2b(d1 * rstd * ldin(g, lane + 64, f32)  + ldin(b, lane + 64, f32));
  o[lane + 128] = f2b(d2 * rstd * ldin(g, lane + 128, f32) + ldin(b, lane + 128, f32));
}

// ---------------------------------------------------------------------------
// LayerNorm (standalone, proven): fp32 in, bf16 out
// ---------------------------------------------------------------------------
__global__ void ln_kernel(const float* __restrict__ in, bf16* __restrict__ out,
                          const void* __restrict__ g, const void* __restrict__ b,
                          int rows, const int* __restrict__ dfl) {
  int f32 = *dfl;
  int wave = (blockIdx.x * blockDim.x + threadIdx.x) >> 6;
  int lane = threadIdx.x & 63;
  if (wave >= rows) return;
  const float* r = in + (size_t)wave * CC;
  float v0 = r[lane], v1 = r[lane + 64], v2 = r[lane + 128];
  float s = v0 + v1 + v2;
  for (int off = 32; off; off >>= 1) s += __shfl_xor(s, off);
  float mean = s * (1.0f / CC);
  float d0 = v0 - mean, d1 = v1 - mean, d2 = v2 - mean;
  float q = d0 * d0 + d1 * d1 + d2 * d2;
  for (int off = 32; off; off >>= 1) q += __shfl_xor(q, off);
  float rstd = rsqrtf(q * (1.0f / CC) + 1e-5f);
  bf16* o = out + (size_t)wave * CC;
  o[lane]       = f2b(d0 * rstd * ldin(g, lane, f32)       + ldin(b, lane, f32));
  o[lane + 64]  = f2b(d1 * rstd * ldin(g, lane + 64, f32)  + ldin(b, lane + 64, f32));
  o[lane + 128] = f2b(d2 * rstd * ldin(g, lane + 128, f32) + ldin(b, lane + 128, f32));
}

// ---------------------------------------------------------------------------
// MFMA GEMM (proven r7): A bf16 [M,K], WT bf16 [N,K]. BK=64. TM in {1,2}.
// FINAL: dst[col*NTOK+row] = v + X2[row*CC+col] (dtype by flag)
// ---------------------------------------------------------------------------
template <int TM, bool BIAS, bool GELU, bool RES, bool OUTBF, bool FINAL>
__global__ void gemm_kernel(const bf16* __restrict__ A, const bf16* __restrict__ WT,
                            const void* __restrict__ bias, const float* __restrict__ R,
                            void* __restrict__ Cout, const float* __restrict__ X2,
                            int M, int N, int K, const int* __restrict__ dfl) {
  int f32 = *dfl;
  __shared__ __align__(16) unsigned short As[TM * 64 * 72];
  __shared__ __align__(16) unsigned short Bs[64 * 72];
  int bm = blockIdx.y * (TM * 64), bn = blockIdx.x * 64;
  int tid = threadIdx.x;
  int w = tid >> 6;
  int lane = tid & 63;
  int lm = lane & 15;
  int lk = lane >> 4;

  f32x4 acc[TM][4];
#pragma unroll
  for (int i = 0; i < TM; i++)
#pragma unroll
    for (int j = 0; j < 4; j++) acc[i][j] = (f32x4){0.f, 0.f, 0.f, 0.f};

  const unsigned short* Au = reinterpret_cast<const unsigned short*>(A);
  const unsigned short* Wu = reinterpret_cast<const unsigned short*>(WT);

  for (int k0 = 0; k0 < K; k0 += 64) {
#pragma unroll
    for (int u = 0; u < TM * 2; u++) {
      int unit = tid + u * 256;
      int row = unit >> 3, seg = unit & 7;
      uint4 v = *reinterpret_cast<const uint4*>(
          &Au[(size_t)(bm + row) * K + k0 + seg * 8]);
      *reinterpret_cast<uint4*>(&As[row * 72 + seg * 8]) = v;
    }
#pragma unroll
    for (int u = 0; u < 2; u++) {
      int unit = tid + u * 256;
      int n = unit >> 3, seg = unit & 7;
      uint4 v = *reinterpret_cast<const uint4*>(
          &Wu[(size_t)(bn + n) * K + k0 + seg * 8]);
      *reinterpret_cast<uint4*>(&Bs[n * 72 + seg * 8]) = v;
    }
    __syncthreads();

#pragma unroll
    for (int kc = 0; kc < 2; kc++) {
      bf16x8 af[TM], bfr[4];
#pragma unroll
      for (int tm = 0; tm < TM; tm++)
        af[tm] = *reinterpret_cast<const bf16x8*>(
            &As[(w * (TM * 16) + tm * 16 + lm) * 72 + kc * 32 + lk * 8]);
#pragma unroll
      for (int tn = 0; tn < 4; tn++)
        bfr[tn] = *reinterpret_cast<const bf16x8*>(
            &Bs[(tn * 16 + lm) * 72 + kc * 32 + lk * 8]);
#pragma unroll
      for (int tm = 0; tm < TM; tm++)
#pragma unroll
        for (int tn = 0; tn < 4; tn++)
          acc[tm][tn] = __builtin_amdgcn_mfma_f32_16x16x32_bf16(
              af[tm], bfr[tn], acc[tm][tn], 0, 0, 0);
    }
    __syncthreads();
  }

#pragma unroll
  for (int tn = 0; tn < 4; tn++) {
    int col = bn + tn * 16 + lm;
    float bv = BIAS ? ldin(bias, col, f32) : 0.f;
#pragma unroll
    for (int tm = 0; tm < TM; tm++) {
      int row0 = bm + w * (TM * 16) + tm * 16 + lk * 4;
#pragma unroll
      for (int r = 0; r < 4; r++) {
        int row = row0 + r;
        float v = acc[tm][tn][r];
        if (BIAS) v += bv;
        if (GELU) v = 0.5f * v * (1.0f + erff(v * 0.70710678118654752f));
        size_t idx = (size_t)row * N + col;
        if (RES) v += R[idx];
        if (FINAL) {
          float o = v + X2[(size_t)row * CC + col];
          if (f32) ((float*)Cout)[(size_t)col * NTOK + row] = o;
          else     ((bf16*)Cout)[(size_t)col * NTOK + row] = f2b(o);
        } else if (OUTBF) {
          ((bf16*)Cout)[idx] = f2b(v);
        } else {
          ((float*)Cout)[idx] = v;
        }
      }
    }
  }
}

// ---------------------------------------------------------------------------
// Time attention (proven): one block per sequence n (1024), 192 threads
// ---------------------------------------------------------------------------
__global__ void time_attn_kernel(const bf16* __restrict__ qkv, bf16* __restrict__ O) {
  __shared__ float q[NHEAD][DD][HDIM];
  __shared__ float k[NHEAD][DD][HDIM];
  __shared__ float v[NHEAD][DD][HDIM];
  __shared__ float p[NHEAD][DD][DD];
  int n = blockIdx.x;
  int head = threadIdx.x >> 5;
  int dd = threadIdx.x & 31;
  for (int s = 0; s < DD; s++) {
    const bf16* row = qkv + (size_t)(n * DD + s) * (3 * CC);
    q[head][s][dd] = b2f(row[head * HDIM + dd]);
    k[head][s][dd] = b2f(row[CC + head * HDIM + dd]);
    v[head][s][dd] = b2f(row[2 * CC + head * HDIM + dd]);
  }
  __syncthreads();
  for (int pair = dd; pair < 64; pair += 32) {
    int sq = pair >> 3, sk = pair & 7;
    float sum = 0.f;
#pragma unroll
    for (int e = 0; e < HDIM; e++) sum += q[head][sq][e] * k[head][sk][e];
    p[head][sq][sk] = sum * ATT_SCALE;
  }
  __syncthreads();
  if (dd < DD) {
    float mx = -1e30f;
    for (int sk = 0; sk < DD; sk++) mx = fmaxf(mx, p[head][dd][sk]);
    float sum = 0.f;
    for (int sk = 0; sk < DD; sk++) { float e = expf(p[head][dd][sk] - mx); p[head][dd][sk] = e; sum += e; }
    float inv = 1.0f / sum;
    for (int sk = 0; sk < DD; sk++) p[head][dd][sk] *= inv;
  }
  __syncthreads();
  for (int sq = 0; sq < DD; sq++) {
    float sum = 0.f;
#pragma unroll
    for (int sk = 0; sk < DD; sk++) sum += p[head][sq][sk] * v[head][sk][dd];
    O[(size_t)(n * DD + sq) * CC + head * HDIM + dd] = f2b(sum);
  }
}

// ---------------------------------------------------------------------------
// Fused time epilogue + space ln1 (proven r7)
// ---------------------------------------------------------------------------
__global__ void epi_ln1_kernel(const float* __restrict__ T, const void* __restrict__ x,
                               const void* __restrict__ gf, const void* __restrict__ bf,
                               const void* __restrict__ g1, const void* __restrict__ b1,
                               float* __restrict__ X1T, bf16* __restrict__ Y,
                               const int* __restrict__ dfl) {
  int f32 = *dfl;
  int wave = (blockIdx.x * blockDim.x + threadIdx.x) >> 6;
  int lane = threadIdx.x & 63;
  if (wave >= NTOK) return;
  const float* r = T + (size_t)wave * CC;
  float v0 = r[lane], v1 = r[lane + 64], v2 = r[lane + 128];
  float s = v0 + v1 + v2;
  for (int off = 32; off; off >>= 1) s += __shfl_xor(s, off);
  float mean = s * (1.0f / CC);
  float d0 = v0 - mean, d1 = v1 - mean, d2 = v2 - mean;
  float q = d0 * d0 + d1 * d1 + d2 * d2;
  for (int off = 32; off; off >>= 1) q += __shfl_xor(q, off);
  float rstd = rsqrtf(q * (1.0f / CC) + 1e-5f);
  int d = wave & 7, hw = wave >> 3;
  int m = d * 1024 + hw;
  float xv[3];
#pragma unroll
  for (int e = 0; e < 3; e++) {
    int c = lane + e * 64;
    float dv = (e == 0 ? d0 : (e == 1 ? d1 : d2));
    float normed = dv * rstd * ldin(gf, c, f32) + ldin(bf, c, f32);
    xv[e] = ldin(x, (size_t)((c << 3) + d) * 1024 + hw, f32) + normed;
  }
  float* o = X1T + (size_t)m * CC;
#pragma unroll
  for (int e = 0; e < 3; e++) o[lane + e * 64] = xv[e];
  float s2 = xv[0] + xv[1] + xv[2];
  for (int off = 32; off; off >>= 1) s2 += __shfl_xor(s2, off);
  float mean2 = s2 * (1.0f / CC);
  float e0 = xv[0] - mean2, e1 = xv[1] - mean2, e2 = xv[2] - mean2;
  float q2 = e0 * e0 + e1 * e1 + e2 * e2;
  for (int off = 32; off; off >>= 1) q2 += __shfl_xor(q2, off);
  float rstd2 = rsqrtf(q2 * (1.0f / CC) + 1e-5f);
  bf16* y = Y + (size_t)m * CC;
  y[lane]       = f2b(e0 * rstd2 * ldin(g1, lane, f32)       + ldin(b1, lane, f32));
  y[lane + 64]  = f2b(e1 * rstd2 * ldin(g1, lane + 64, f32)  + ldin(b1, lane + 64, f32));
  y[lane + 128] = f2b(e2 * rstd2 * ldin(g1, lane + 128, f32) + ldin(b1, lane + 128, f32));
}

// ---------------------------------------------------------------------------
// MFMA NAT attention (proven r6). Block = (frame, 8x8 tile, head), 768 blocks.
// ---------------------------------------------------------------------------
#define NKEY 224
#define PKS 40
#define PVS 232
__global__ void nat_attn_kernel(const bf16* __restrict__ qkv, const void* __restrict__ rpb,
                                bf16* __restrict__ O, const int* __restrict__ dfl) {
  int f32 = *dfl;
  __shared__ __align__(16) unsigned short Ks[NKEY * PKS];
  __shared__ __align__(16) unsigned short Vs[32 * PVS];
  __shared__ __align__(16) unsigned short Qs[64 * PKS];
  __shared__ __align__(16) unsigned short Ps[64 * PVS];
  __shared__ float rb[176];

  int blk = blockIdx.x;
  int frame = blk & 7;
  int rest = blk >> 3;
  int h = rest % 6;
  int tile = rest / 6;
  int ty = tile >> 2, tx = tile & 3;
  int base_h = min(max(ty * 8 - 3, 0), HH - 7);
  int base_w = min(max(tx * 8 - 3, 0), WW - 7);

  int tid = threadIdx.x;

  for (int i = tid; i < 169; i += 256) rb[i] = ldin(rpb, (size_t)h * 169 + i, f32);
  for (int u = tid; u < 784; u += 256) {
    int j = u >> 2, seg = u & 3;
    int a = j / 14, bb = j - a * 14;
    int ih = min(base_h + a, HH - 1), iw = min(base_w + bb, WW - 1);
    int mg = frame * 1024 + ih * 32 + iw;
    uint4 v = *reinterpret_cast<const uint4*>(qkv + (size_t)mg * 576 + 192 + h * 32 + seg * 8);
    *reinterpret_cast<uint4*>(&Ks[j * PKS + seg * 8]) = v;
  }
  for (int u = tid; u < 784; u += 256) {
    int j = u >> 2, seg = u & 3;
    int a = j / 14, bb = j - a * 14;
    int ih = min(base_h + a, HH - 1), iw = min(base_w + bb, WW - 1);
    int mg = frame * 1024 + ih * 32 + iw;
    uint4 v = *reinterpret_cast<const uint4*>(qkv + (size_t)mg * 576 + 384 + h * 32 + seg * 8);
    unsigned arr[4] = {v.x, v.y, v.z, v.w};
#pragma unroll
    for (int e = 0; e < 4; e++) {
      Vs[(seg * 8 + e * 2) * PVS + j]     = (unsigned short)(arr[e] & 0xffffu);
      Vs[(seg * 8 + e * 2 + 1) * PVS + j] = (unsigned short)(arr[e] >> 16);
    }
  }
  for (int u = tid; u < 32 * (PVS - 196); u += 256) {
    int dd = u / (PVS - 196), c = 196 + u % (PVS - 196);
    Vs[dd * PVS + c] = 0;
  }
  {
    int q = tid >> 2, seg = tid & 3;
    int qy = ty * 8 + (q >> 3), qx = tx * 8 + (q & 7);
    int mg = frame * 1024 + qy * 32 + qx;
    uint4 v = *reinterpret_cast<const uint4*>(qkv + (size_t)mg * 576 + h * 32 + seg * 8);
    *reinterpret_cast<uint4*>(&Qs[q * PKS + seg * 8]) = v;
  }
  __syncthreads();

  int w = tid >> 6;
  int lane = tid & 63;
  int c = lane & 15;
  int lk = lane >> 4;

  bf16x8 aq = *reinterpret_cast<const bf16x8*>(&Qs[(w * 16 + c) * PKS + lk * 8]);
  f32x4 sc[14];
#pragma unroll
  for (int f = 0; f < 14; f++) {
    bf16x8 bk = *reinterpret_cast<const bf16x8*>(&Ks[(f * 16 + c) * PKS + lk * 8]);
    sc[f] = __builtin_amdgcn_mfma_f32_16x16x32_bf16(aq, bk, (f32x4){0.f, 0.f, 0.f, 0.f}, 0, 0, 0);
  }

#pragma unroll
  for (int f = 0; f < 14; f++) {
    int key = f * 16 + c;
    int a = key / 14, bb = key - a * 14;
    int ih = base_h + a, iw = base_w + bb;
    bool keyok = key < 196;
#pragma unroll
    for (int r = 0; r < 4; r++) {
      int qloc = w * 16 + lk * 4 + r;
      int qy = ty * 8 + (qloc >> 3), qx = tx * 8 + (qloc & 7);
      int sh = min(max(qy - 3, 0), HH - 7);
      int sw = min(max(qx - 3, 0), WW - 7);
      bool valid = keyok && ((unsigned)(ih - sh) < 7u) && ((unsigned)(iw - sw) < 7u);
      int bidx = valid ? (ih - qy + 6) * 13 + (iw - qx + 6) : 0;
      float s = sc[f][r] * ATT_SCALE + rb[bidx];
      sc[f][r] = valid ? s : -1e30f;
    }
  }

  float sm[4];
#pragma unroll
  for (int r = 0; r < 4; r++) {
    float m = sc[0][r];
#pragma unroll
    for (int f = 1; f < 14; f++) m = fmaxf(m, sc[f][r]);
    for (int off = 8; off; off >>= 1) m = fmaxf(m, __shfl_xor(m, off));
    float s = 0.f;
#pragma unroll
    for (int f = 0; f < 14; f++) { float e = __expf(sc[f][r] - m); sc[f][r] = e; s += e; }
    for (int off = 8; off; off >>= 1) s += __shfl_xor(s, off);
    sm[r] = 1.0f / s;
  }
#pragma unroll
  for (int f = 0; f < 14; f++)
#pragma unroll
    for (int r = 0; r < 4; r++)
      Ps[(w * 16 + lk * 4 + r) * PVS + f * 16 + c] = f2us(sc[f][r] * sm[r]);
  __syncthreads();

  f32x4 oacc[2] = {(f32x4){0.f, 0.f, 0.f, 0.f}, (f32x4){0.f, 0.f, 0.f, 0.f}};
#pragma unroll
  for (int kt = 0; kt < 7; kt++) {
    bf16x8 ap = *reinterpret_cast<const bf16x8*>(&Ps[(w * 16 + c) * PVS + kt * 32 + lk * 8]);
#pragma unroll
    for (int dt = 0; dt < 2; dt++) {
      bf16x8 bv = *reinterpret_cast<const bf16x8*>(&Vs[(dt * 16 + c) * PVS + kt * 32 + lk * 8]);
      oacc[dt] = __builtin_amdgcn_mfma_f32_16x16x32_bf16(ap, bv, oacc[dt], 0, 0, 0);
    }
  }

#pragma unroll
  for (int dt = 0; dt < 2; dt++)
#pragma unroll
    for (int r = 0; r < 4; r++) {
      int qloc = w * 16 + lk * 4 + r;
      int qy = ty * 8 + (qloc >> 3), qx = tx * 8 + (qloc & 7);
      int mg = frame * 1024 + qy * 32 + qx;
      O[(size_t)mg * CC + h * 32 + dt * 16 + c] = f2b(oacc[dt][r]);
    }
}

// ---------------------------------------------------------------------------
extern "C" void kernel_launch(void* const* d_in, const int* in_sizes, int n_in,
                              void* d_out, int out_size, void* d_ws, size_t ws_size,
                              hipStream_t stream) {
  const void* x        = d_in[0];
  const void* pos_emb  = d_in[1];
  const void* t_ln1_g  = d_in[2];
  const void* t_ln1_b  = d_in[3];
  const void* t_qkv_w  = d_in[4];
  const void* t_out_w  = d_in[5];
  const void* t_out_b  = d_in[6];
  const void* t_ln2_g  = d_in[7];
  const void* t_ln2_b  = d_in[8];
  const void* t_fc1_w  = d_in[9];
  const void* t_fc1_b  = d_in[10];
  const void* t_fc2_w  = d_in[11];
  const void* t_fc2_b  = d_in[12];
  const void* t_lnf_g  = d_in[13];
  const void* t_lnf_b  = d_in[14];
  const void* s_ln1_g  = d_in[15];
  const void* s_ln1_b  = d_in[16];
  const void* s_qkv_w  = d_in[17];
  const void* s_qkv_b  = d_in[18];
  const void* s_rpb    = d_in[19];
  const void* s_proj_w = d_in[20];
  const void* s_proj_b = d_in[21];
  const void* s_ln2_g  = d_in[22];
  const void* s_ln2_b  = d_in[23];
  const void* s_fc1_w  = d_in[24];
  const void* s_fc1_b  = d_in[25];
  const void* s_fc2_w  = d_in[26];
  const void* s_fc2_b  = d_in[27];

  // Workspace: [0,SZ) f32 T/S | [SZ,2SZ) f32 X1T | [2SZ,2.5SZ) bf16 Y |
  // [2.5SZ,3SZ) bf16 O | [3SZ,5SZ) bf16 QKV/Hb | [5SZ] dfl | WT bf16.
  float* ws = (float*)d_ws;
  const size_t SZ = (size_t)NTOK * CC;
  const size_t need = (5 * SZ + 4 + 442368 + 16) * sizeof(float);
  if (ws_size < need) return;

  float* T   = ws;
  float* X1T = ws + SZ;
  bf16*  Y   = (bf16*)(ws + 2 * SZ);
  bf16*  O   = (bf16*)(ws + 2 * SZ + SZ / 2);
  bf16*  QKV = (bf16*)(ws + 3 * SZ);
  bf16*  Hb  = QKV;
  float* S   = T;
  int*   dfl = (int*)(ws + 5 * SZ);
  bf16*  WT  = (bf16*)(ws + 5 * SZ + 4);

  dim3 blk256(256);

  wconv_kernel<<<3456, blk256, 0, stream>>>(
      (const unsigned short*)x,
      t_qkv_w, t_out_w, t_fc1_w, t_fc2_w, s_qkv_w, s_proj_w, s_fc1_w, s_fc2_w, WT, dfl);

  // ---- Time transformer ----
  build_ln1_kernel<<<NTOK / 4, blk256, 0, stream>>>(x, pos_emb, t_ln1_g, t_ln1_b, T, Y, dfl);
  gemm_kernel<2, false, false, false, true, false><<<dim3(9, 64), blk256, 0, stream>>>(
      Y, WT + WOFF_TQKV, nullptr, nullptr, QKV, nullptr, NTOK, 3 * CC, CC, dfl);
  time_attn_kernel<<<1024, 192, 0, stream>>>(QKV, O);
  gemm_kernel<1, true, false, true, false, false><<<dim3(3, 128), blk256, 0, stream>>>(
      O, WT + WOFF_TOUT, t_out_b, T, T, nullptr, NTOK, CC, CC, dfl);
  ln_kernel<<<NTOK / 4, blk256, 0, stream>>>(T, Y, t_ln2_g, t_ln2_b, NTOK, dfl);
  gemm_kernel<2, true, true, false, true, false><<<dim3(12, 64), blk256, 0, stream>>>(
      Y, WT + WOFF_TFC1, t_fc1_b, nullptr, Hb, nullptr, NTOK, HID, CC, dfl);
  gemm_kernel<1, true, false, true, false, false><<<dim3(3, 128), blk256, 0, stream>>>(
      Hb, WT + WOFF_TFC2, t_fc2_b, T, T, nullptr, NTOK, CC, HID, dfl);
  epi_ln1_kernel<<<NTOK / 4, blk256, 0, stream>>>(
      T, x, t_lnf_g, t_lnf_b, s_ln1_g, s_ln1_b, X1T, Y, dfl);

  // ---- Space transformer ----
  gemm_kernel<2, true, false, false, true, false><<<dim3(9, 64), blk256, 0, stream>>>(
      Y, WT + WOFF_SQKV, s_qkv_b, nullptr, QKV, nullptr, NTOK, 3 * CC, CC, dfl);
  nat_attn_kernel<<<768, blk256, 0, stream>>>(QKV, s_rpb, O, dfl);
  gemm_kernel<1, true, false, true, false, false><<<dim3(3, 128), blk256, 0, stream>>>(
      O, WT + WOFF_SPROJ, s_proj_b, X1T, S, nullptr, NTOK, CC, CC, dfl);
  ln_kernel<<<NTOK / 4, blk256, 0, stream>>>(S, Y, s_ln2_g, s_ln2_b, NTOK, dfl);
  gemm_kernel<2, true, true, false, true, false><<<dim3(12, 64), blk256, 0, stream>>>(
      Y, WT + WOFF_SFC1, s_fc1_b, nullptr, Hb, nullptr, NTOK, HID, CC, dfl);
  gemm_kernel<1, true, false, true, false, true><<<dim3(3, 128), blk256, 0, stream>>>(
      Hb, WT + WOFF_SFC2, s_fc2_b, S, d_out, X1T, NTOK, CC, HID, dfl);
}